// Round 12
// baseline (1989.440 us; speedup 1.0000x reference)
//
#include <hip/hip_runtime.h>
#include <cstdint>

#define B_DIM 32
#define T_DIM 1024
#define NIN 128
#define NG 16       // i-groups of 8
#define NHID 1024
#define KSLOT 8
#define NWORDS 34   // 2 guard words (64 zero bits) + 32 data words
#define WAVES 8
#define CHUNKS 32
#define ROUNDS (CHUNKS / WAVES)
#define WSCALE 16.0f

// Per-k&3 conversion scales for the mask-ladder (masks 1/2/4/8 give 1x/2x/4x/-8x sums;
// nibble 0x8 is -8 as signed i4, folded into a negative scale). All exact powers of 2.
#define SC0 (1.0f / 16.0f)
#define SC1 (1.0f / 32.0f)
#define SC2 (1.0f / 64.0f)
#define SC3 (-1.0f / 128.0f)

// 8 x i4 MAC in one instruction (v_dot8_i32_i4). Fallback preserves semantics.
__device__ __forceinline__ int dot8acc(uint32_t sel, uint32_t wq, int acc) {
#if __has_builtin(__builtin_amdgcn_sdot8)
    return __builtin_amdgcn_sdot8((int)sel, (int)wq, acc, false);
#else
    #pragma unroll
    for (int m = 0; m < 8; ++m) {
        int s = ((int)((sel >> (4 * m)) & 0xF) << 28) >> 28;   // signed i4
        int q = ((int)((wq  >> (4 * m)) & 0xF) << 28) >> 28;   // signed i4
        acc += s * q;
    }
    return acc;
#endif
}

__device__ __forceinline__ uint32_t permb(uint32_t hi, uint32_t lo, uint32_t sel) {
#if __has_builtin(__builtin_amdgcn_perm)
    return __builtin_amdgcn_perm(hi, lo, sel);   // S0=hi(bytes 7..4), S1=lo(bytes 3..0)
#else
    union { uint32_t w[2]; unsigned char b[8]; } src;
    src.w[0] = lo; src.w[1] = hi;
    uint32_t r = 0;
    for (int n = 0; n < 4; ++n) r |= (uint32_t)src.b[(sel >> (8 * n)) & 7] << (8 * n);
    return r;
#endif
}

__device__ __forceinline__ uint32_t funnel32(uint32_t hi, uint32_t lo, uint32_t sh) {
#if __has_builtin(__builtin_amdgcn_alignbit)
    return __builtin_amdgcn_alignbit(hi, lo, sh);   // ((hi:lo) >> (sh&31)) low 32
#else
    return (uint32_t)(((((uint64_t)hi) << 32) | lo) >> (sh & 31));
#endif
}

// window for one stream: pick word pair by (sp>=32), funnel by sp&31
__device__ __forceinline__ uint32_t mkwin(uint32_t sp, uint32_t wa, uint32_t wb, uint32_t wc) {
    uint32_t lo = (sp >= 32u) ? wb : wa;
    uint32_t hi = (sp >= 32u) ? wc : wb;
    return funnel32(hi, lo, sp);
}

// ---------------- merged prep kernel ----------------
// blocks   0..511: pack spike bits TRANSPOSED: xbitsT[b][w][i]
// blocks 512..575: packed per-(g,h) params: {sp bytes lo, sp bytes hi, wq nibbles, pad}
//                  (sp = 63 - delay; wq nibble order [0,4,1,5,2,6,3,7])
// blocks 576..580: init out (logits = bias, totals = 0)
__global__ void prep_kernel(const float* __restrict__ x, const float* __restrict__ W,
                            const float* __restrict__ draw, const float* __restrict__ b_ro,
                            uint32_t* __restrict__ xbitsT, uint4* __restrict__ pk4,
                            float* __restrict__ out) {
    int blk = blockIdx.x, tid = threadIdx.x;
    if (blk < 512) {
        int idx = blk * 256 + tid;        // 131072 = b*4096 + w*128 + i
        int b = idx >> 12, w = (idx >> 7) & 31, i = idx & 127;
        const float* xp = x + (size_t)b * T_DIM * NIN + (size_t)w * 32 * NIN + i;
        uint32_t word = 0;
        #pragma unroll
        for (int bit = 0; bit < 32; ++bit) {
            float xv = xp[(size_t)bit * NIN];   // lanes = consecutive i -> coalesced
            word |= (xv != 0.0f) ? (1u << bit) : 0u;
        }
        uint32_t* bp = xbitsT + (size_t)b * NWORDS * NIN;
        bp[(2 + w) * NIN + i] = word;           // transposed: [w][i]
        if (w == 0) { bp[i] = 0u; bp[NIN + i] = 0u; }   // guard rows
    } else if (blk < 576) {
        int idx = (blk - 512) * 256 + tid;    // 16384 = g*1024 + h
        int g = idx >> 10, h = idx & 1023;
        const float* Wp = W    + (size_t)h * NIN + 8 * g;
        const float* Rp = draw + (size_t)h * NIN + 8 * g;
        uint32_t s0 = 0, s1 = 0, wq = 0;
        const int ordm[8] = {0, 4, 1, 5, 2, 6, 3, 7};
        #pragma unroll
        for (int j = 0; j < 4; ++j) {
            int sp_a = 63 - (int)rintf(50.0f / (1.0f + expf(-Rp[j])));      // RNE = jnp.round
            int sp_b = 63 - (int)rintf(50.0f / (1.0f + expf(-Rp[4 + j])));
            s0 |= (uint32_t)sp_a << (8 * j);
            s1 |= (uint32_t)sp_b << (8 * j);
        }
        #pragma unroll
        for (int m = 0; m < 8; ++m) {
            int q = (int)rintf(fminf(fmaxf(Wp[ordm[m]] * WSCALE, -8.0f), 7.0f));
            wq |= ((uint32_t)q & 0xFu) << (4 * m);
        }
        pk4[(size_t)g * NHID + h] = make_uint4(s0, s1, wq, 0u);
    } else {
        int idx = (blk - 576) * 256 + tid;    // 1280 outputs
        if (idx < B_DIM * KSLOT) out[idx] = b_ro[0];
        else if (idx < B_DIM * KSLOT + T_DIM) out[idx] = 0.0f;
    }
}

// ---------------- fused sdot8 mask-ladder + wave-relay LIF ----------------
// block = (b, hg of 64 h), 512 threads = 8 waves, grid 512.
// R12: software-pipelined g-loop (fully unrolled, g+1 loads issued before g's compute)
// to hide LDS latency — diagnosis: real VALU occupancy ~37% (gfx94x VALUBusy formula
// assumes SIMD-16; divide by 2), so the kernel is latency-stalled, not issue-bound.
__global__ __launch_bounds__(512, 4) void fused_kernel(
    const uint4* __restrict__ pk4, const uint32_t* __restrict__ xbitsT,
    float* __restrict__ out, const float* __restrict__ w_ro,
    const int* __restrict__ ss, const int* __restrict__ se) {
    __shared__ uint32_t lds_x[NWORDS * NIN];  // [w][i]   17 KB (transposed)
    __shared__ uint4    lds_pk[NG * 64];      // [g][hl]  16 KB {sp lo, sp hi, wq, pad}
    __shared__ float st_v[64];
    __shared__ float st_rf[64];
    __shared__ float st_sacc[KSLOT][64];      // authoritative (lazy relay)
    __shared__ int   flag;

    int bx = blockIdx.x;
    int hg = bx & 15;
    int b  = bx >> 4;
    int tid  = threadIdx.x;
    int lane = tid & 63;
    int sub  = tid >> 6;
    int hbase = hg * 64;

    for (int idx = tid; idx < NWORDS * NIN; idx += 512)
        lds_x[idx] = xbitsT[(size_t)b * NWORDS * NIN + idx];
    for (int idx = tid; idx < NG * 64; idx += 512) {
        int g = idx >> 6, hl = idx & 63;
        lds_pk[idx] = pk4[(size_t)g * NHID + hbase + hl];
    }
    if (tid < 64) { st_v[tid] = 0.0f; st_rf[tid] = 0.0f; }
    if (tid < KSLOT * 64) ((float*)st_sacc)[tid] = 0.0f;
    if (tid == 0) flag = 0;
    __syncthreads();

    int st_[KSLOT], en_[KSLOT];
    #pragma unroll
    for (int k = 0; k < KSLOT; ++k) {
        st_[k] = __builtin_amdgcn_readfirstlane(ss[k]);
        en_[k] = __builtin_amdgcn_readfirstlane(se[k]);
    }

    for (int rl = 0; rl < ROUNDS; ++rl) {
        int c  = __builtin_amdgcn_readfirstlane(rl * WAVES + sub);
        int t0 = c * 32;
        int acc[32];
        #pragma unroll
        for (int k = 0; k < 32; ++k) acc[k] = 0;
        const uint32_t* xrow = lds_x + c * NIN;   // per-chunk base; all offsets immediate
        // ---- software pipeline: preload g=0 ----
        uint4 pk = lds_pk[lane];
        uint4 ra0 = *(const uint4*)(xrow);
        uint4 rb0 = *(const uint4*)(xrow + NIN);
        uint4 rc0 = *(const uint4*)(xrow + 2 * NIN);
        uint4 ra1 = *(const uint4*)(xrow + 4);
        uint4 rb1 = *(const uint4*)(xrow + NIN + 4);
        uint4 rc1 = *(const uint4*)(xrow + 2 * NIN + 4);
        #pragma unroll
        for (int g = 0; g < NG; ++g) {
            // current working copies
            uint4 pkc = pk;
            uint4 a0 = ra0, b0 = rb0, c0 = rc0, a1 = ra1, b1 = rb1, c1 = rc1;
            // issue g+1's loads now; results awaited only at next iteration's use
            if (g + 1 < NG) {
                pk  = lds_pk[((g + 1) << 6) | lane];
                ra0 = *(const uint4*)(xrow + 8 * (g + 1));
                rb0 = *(const uint4*)(xrow + NIN + 8 * (g + 1));
                rc0 = *(const uint4*)(xrow + 2 * NIN + 8 * (g + 1));
                ra1 = *(const uint4*)(xrow + 8 * (g + 1) + 4);
                rb1 = *(const uint4*)(xrow + NIN + 8 * (g + 1) + 4);
                rc1 = *(const uint4*)(xrow + 2 * NIN + 8 * (g + 1) + 4);
            }
            uint32_t wq = pkc.z;
            uint32_t win[8];
            win[0] = mkwin(pkc.x & 0xFFu,         a0.x, b0.x, c0.x);
            win[1] = mkwin((pkc.x >> 8) & 0xFFu,  a0.y, b0.y, c0.y);
            win[2] = mkwin((pkc.x >> 16) & 0xFFu, a0.z, b0.z, c0.z);
            win[3] = mkwin(pkc.x >> 24,           a0.w, b0.w, c0.w);
            win[4] = mkwin(pkc.y & 0xFFu,         a1.x, b1.x, c1.x);
            win[5] = mkwin((pkc.y >> 8) & 0xFFu,  a1.y, b1.y, c1.y);
            win[6] = mkwin((pkc.y >> 16) & 0xFFu, a1.z, b1.z, c1.z);
            win[7] = mkwin(pkc.y >> 24,           a1.w, b1.w, c1.w);
            // ---- byte-interleave; X nibble order [s0,s4,s1,s5,s2,s6,s3,s7] = wq packing ----
            uint32_t A0 = permb(win[1], win[0], 0x05010400u);
            uint32_t B0 = permb(win[1], win[0], 0x07030602u);
            uint32_t C0 = permb(win[3], win[2], 0x05010400u);
            uint32_t D0 = permb(win[3], win[2], 0x07030602u);
            uint32_t A1 = permb(win[5], win[4], 0x05010400u);
            uint32_t B1 = permb(win[5], win[4], 0x07030602u);
            uint32_t C1 = permb(win[7], win[6], 0x05010400u);
            uint32_t D1 = permb(win[7], win[6], 0x07030602u);
            {
                uint32_t P = permb(C0, A0, 0x05040100u);
                uint32_t Q = permb(C1, A1, 0x05040100u);
                uint32_t X0 = (P & 0x0F0F0F0Fu) | ((Q << 4) & 0xF0F0F0F0u);
                uint32_t X1 = ((P >> 4) & 0x0F0F0F0Fu) | (Q & 0xF0F0F0F0u);
                acc[0] = dot8acc(X0 & 0x11111111u, wq, acc[0]);   // 1x
                acc[1] = dot8acc(X0 & 0x22222222u, wq, acc[1]);   // 2x
                acc[2] = dot8acc(X0 & 0x44444444u, wq, acc[2]);   // 4x
                acc[3] = dot8acc(X0 & 0x88888888u, wq, acc[3]);   // -8x
                acc[4] = dot8acc(X1 & 0x11111111u, wq, acc[4]);
                acc[5] = dot8acc(X1 & 0x22222222u, wq, acc[5]);
                acc[6] = dot8acc(X1 & 0x44444444u, wq, acc[6]);
                acc[7] = dot8acc(X1 & 0x88888888u, wq, acc[7]);
            }
            {
                uint32_t P = permb(C0, A0, 0x07060302u);
                uint32_t Q = permb(C1, A1, 0x07060302u);
                uint32_t X2 = (P & 0x0F0F0F0Fu) | ((Q << 4) & 0xF0F0F0F0u);
                uint32_t X3 = ((P >> 4) & 0x0F0F0F0Fu) | (Q & 0xF0F0F0F0u);
                acc[8]  = dot8acc(X2 & 0x11111111u, wq, acc[8]);
                acc[9]  = dot8acc(X2 & 0x22222222u, wq, acc[9]);
                acc[10] = dot8acc(X2 & 0x44444444u, wq, acc[10]);
                acc[11] = dot8acc(X2 & 0x88888888u, wq, acc[11]);
                acc[12] = dot8acc(X3 & 0x11111111u, wq, acc[12]);
                acc[13] = dot8acc(X3 & 0x22222222u, wq, acc[13]);
                acc[14] = dot8acc(X3 & 0x44444444u, wq, acc[14]);
                acc[15] = dot8acc(X3 & 0x88888888u, wq, acc[15]);
            }
            {
                uint32_t P = permb(D0, B0, 0x05040100u);
                uint32_t Q = permb(D1, B1, 0x05040100u);
                uint32_t X4 = (P & 0x0F0F0F0Fu) | ((Q << 4) & 0xF0F0F0F0u);
                uint32_t X5 = ((P >> 4) & 0x0F0F0F0Fu) | (Q & 0xF0F0F0F0u);
                acc[16] = dot8acc(X4 & 0x11111111u, wq, acc[16]);
                acc[17] = dot8acc(X4 & 0x22222222u, wq, acc[17]);
                acc[18] = dot8acc(X4 & 0x44444444u, wq, acc[18]);
                acc[19] = dot8acc(X4 & 0x88888888u, wq, acc[19]);
                acc[20] = dot8acc(X5 & 0x11111111u, wq, acc[20]);
                acc[21] = dot8acc(X5 & 0x22222222u, wq, acc[21]);
                acc[22] = dot8acc(X5 & 0x44444444u, wq, acc[22]);
                acc[23] = dot8acc(X5 & 0x88888888u, wq, acc[23]);
            }
            {
                uint32_t P = permb(D0, B0, 0x07060302u);
                uint32_t Q = permb(D1, B1, 0x07060302u);
                uint32_t X6 = (P & 0x0F0F0F0Fu) | ((Q << 4) & 0xF0F0F0F0u);
                uint32_t X7 = ((P >> 4) & 0x0F0F0F0Fu) | (Q & 0xF0F0F0F0u);
                acc[24] = dot8acc(X6 & 0x11111111u, wq, acc[24]);
                acc[25] = dot8acc(X6 & 0x22222222u, wq, acc[25]);
                acc[26] = dot8acc(X6 & 0x44444444u, wq, acc[26]);
                acc[27] = dot8acc(X6 & 0x88888888u, wq, acc[27]);
                acc[28] = dot8acc(X7 & 0x11111111u, wq, acc[28]);
                acc[29] = dot8acc(X7 & 0x22222222u, wq, acc[29]);
                acc[30] = dot8acc(X7 & 0x44444444u, wq, acc[30]);
                acc[31] = dot8acc(X7 & 0x88888888u, wq, acc[31]);
            }
        }
        // ---- relay: wait for token ----
        while (__builtin_amdgcn_readfirstlane(*(volatile int*)&flag) != c)
            __builtin_amdgcn_s_sleep(1);
        float v  = st_v[lane];
        float rf = st_rf[lane];
        // ---- LIF fast path (exact detection of slow-path need) ----
        float vf = v, vmax = -1.0f;
        #pragma unroll
        for (int k = 0; k < 32; ++k) {
            float sc = ((k & 3) == 0) ? SC0 : ((k & 3) == 1) ? SC1 : ((k & 3) == 2) ? SC2 : SC3;
            float I = (float)acc[k] * sc;
            vf = vf + 0.1f * (I - vf);
            vmax = fmaxf(vmax, vf);
        }
        bool slow = (rf > 0.0f) || (vmax >= 1.0f);
        if (__ballot(slow) != 0ULL) {
            // ---- exact path (rare: >=7 sigma margin) ----
            float sacc[KSLOT];
            #pragma unroll
            for (int k = 0; k < KSLOT; ++k) sacc[k] = st_sacc[k][lane];
            #pragma unroll
            for (int k = 0; k < 32; ++k) {
                float sc = ((k & 3) == 0) ? SC0 : ((k & 3) == 1) ? SC1 : ((k & 3) == 2) ? SC2 : SC3;
                float I = (float)acc[k] * sc;
                int t = t0 + k;
                bool active = (rf <= 0.0f);
                float vupd = v + 0.1f * (I - v);
                float vn = active ? vupd : v;
                bool spike = active && (vn >= 1.0f);
                unsigned long long bal = __ballot(spike);
                if (bal != 0ULL) {
                    if (spike) {
                        vn = 0.0f;                // V_RESET
                        #pragma unroll
                        for (int k2 = 0; k2 < KSLOT; ++k2)
                            if (t >= st_[k2] && t < en_[k2]) sacc[k2] += 1.0f;
                    }
                    rf = spike ? 2.0f : fmaxf(rf - 1.0f, 0.0f);
                    if (lane == 0) atomicAdd(&out[B_DIM * KSLOT + t], (float)__popcll(bal));
                } else {
                    rf = fmaxf(rf - 1.0f, 0.0f);
                }
                v = vn;
            }
            #pragma unroll
            for (int k = 0; k < KSLOT; ++k) st_sacc[k][lane] = sacc[k];
        } else {
            v = vf;
            rf = 0.0f;
        }
        st_v[lane]  = v;
        st_rf[lane] = rf;
        __threadfence_block();                     // drain LDS writes before flag release
        if (lane == 0) *(volatile int*)&flag = c + 1;
    }
    // ---- epilogue: after chunk 31's relay write, LDS sacc is final ----
    if (sub == WAVES - 1) {
        float wr = w_ro[hbase + lane];
        #pragma unroll
        for (int k = 0; k < KSLOT; ++k) {
            float val = st_sacc[k][lane] * wr;
            #pragma unroll
            for (int o = 32; o > 0; o >>= 1) val += __shfl_down(val, o);
            if (lane == 0) atomicAdd(&out[b * KSLOT + k], val);
        }
    }
}

extern "C" void kernel_launch(void* const* d_in, const int* in_sizes, int n_in,
                              void* d_out, int out_size, void* d_ws, size_t ws_size,
                              hipStream_t stream) {
    const float* x   = (const float*)d_in[0];
    const float* W   = (const float*)d_in[1];
    const float* drw = (const float*)d_in[2];
    const float* wro = (const float*)d_in[3];
    const float* bro = (const float*)d_in[4];
    const int*   ss  = (const int*)d_in[5];
    const int*   se  = (const int*)d_in[6];
    float* out = (float*)d_out;

    uintptr_t base = (uintptr_t)d_ws;
    size_t off = 0;
    auto take = [&](size_t bytes) {
        size_t o = off;
        off = (off + bytes + 255) & ~(size_t)255;
        return (void*)(base + o);
    };
    uint32_t* xbitsT = (uint32_t*)take((size_t)B_DIM * NWORDS * NIN * 4);
    uint4*    pk4    = (uint4*)take((size_t)NG * NHID * 16);
    (void)ws_size;

    prep_kernel<<<581, 256, 0, stream>>>(x, W, drw, bro, xbitsT, pk4, out);
    fused_kernel<<<512, 512, 0, stream>>>(pk4, xbitsT, out, wro, ss, se);
}

// Round 13
// 156.447 us; speedup vs baseline: 12.7164x; 12.7164x over previous
//
#include <hip/hip_runtime.h>
#include <cstdint>

#define B_DIM 32
#define T_DIM 1024
#define NIN 128
#define NG 16       // i-groups of 8
#define NHID 1024
#define KSLOT 8
#define NWORDS 34   // 2 guard words (64 zero bits) + 32 data words
#define WAVES 8
#define CHUNKS 32
#define ROUNDS (CHUNKS / WAVES)
#define WSCALE 16.0f

// Per-k&3 conversion scales for the mask-ladder (masks 1/2/4/8 give 1x/2x/4x/-8x sums;
// nibble 0x8 is -8 as signed i4, folded into a negative scale). All exact powers of 2.
#define SC0 (1.0f / 16.0f)
#define SC1 (1.0f / 32.0f)
#define SC2 (1.0f / 64.0f)
#define SC3 (-1.0f / 128.0f)

// 8 x i4 MAC in one instruction (v_dot8_i32_i4). Fallback preserves semantics.
__device__ __forceinline__ int dot8acc(uint32_t sel, uint32_t wq, int acc) {
#if __has_builtin(__builtin_amdgcn_sdot8)
    return __builtin_amdgcn_sdot8((int)sel, (int)wq, acc, false);
#else
    #pragma unroll
    for (int m = 0; m < 8; ++m) {
        int s = ((int)((sel >> (4 * m)) & 0xF) << 28) >> 28;   // signed i4
        int q = ((int)((wq  >> (4 * m)) & 0xF) << 28) >> 28;   // signed i4
        acc += s * q;
    }
    return acc;
#endif
}

__device__ __forceinline__ uint32_t permb(uint32_t hi, uint32_t lo, uint32_t sel) {
#if __has_builtin(__builtin_amdgcn_perm)
    return __builtin_amdgcn_perm(hi, lo, sel);   // S0=hi(bytes 7..4), S1=lo(bytes 3..0)
#else
    union { uint32_t w[2]; unsigned char b[8]; } src;
    src.w[0] = lo; src.w[1] = hi;
    uint32_t r = 0;
    for (int n = 0; n < 4; ++n) r |= (uint32_t)src.b[(sel >> (8 * n)) & 7] << (8 * n);
    return r;
#endif
}

__device__ __forceinline__ uint32_t funnel32(uint32_t hi, uint32_t lo, uint32_t sh) {
#if __has_builtin(__builtin_amdgcn_alignbit)
    return __builtin_amdgcn_alignbit(hi, lo, sh);   // ((hi:lo) >> (sh&31)) low 32
#else
    return (uint32_t)(((((uint64_t)hi) << 32) | lo) >> (sh & 31));
#endif
}

// window for one stream: pick word pair by (sp>=32), funnel by sp&31
__device__ __forceinline__ uint32_t mkwin(uint32_t sp, uint32_t wa, uint32_t wb, uint32_t wc) {
    uint32_t lo = (sp >= 32u) ? wb : wa;
    uint32_t hi = (sp >= 32u) ? wc : wb;
    return funnel32(hi, lo, sp);
}

// ---------------- merged prep kernel ----------------
// blocks   0..511: pack spike bits TRANSPOSED: xbitsT[b][w][i]
// blocks 512..575: packed per-(g,h) params: {sp bytes lo, sp bytes hi, wq nibbles, pad}
//                  (sp = 63 - delay; wq nibble order [0,4,1,5,2,6,3,7])
// blocks 576..580: init out (logits = bias, totals = 0)
__global__ void prep_kernel(const float* __restrict__ x, const float* __restrict__ W,
                            const float* __restrict__ draw, const float* __restrict__ b_ro,
                            uint32_t* __restrict__ xbitsT, uint4* __restrict__ pk4,
                            float* __restrict__ out) {
    int blk = blockIdx.x, tid = threadIdx.x;
    if (blk < 512) {
        int idx = blk * 256 + tid;        // 131072 = b*4096 + w*128 + i
        int b = idx >> 12, w = (idx >> 7) & 31, i = idx & 127;
        const float* xp = x + (size_t)b * T_DIM * NIN + (size_t)w * 32 * NIN + i;
        uint32_t word = 0;
        #pragma unroll
        for (int bit = 0; bit < 32; ++bit) {
            float xv = xp[(size_t)bit * NIN];   // lanes = consecutive i -> coalesced
            word |= (xv != 0.0f) ? (1u << bit) : 0u;
        }
        uint32_t* bp = xbitsT + (size_t)b * NWORDS * NIN;
        bp[(2 + w) * NIN + i] = word;           // transposed: [w][i]
        if (w == 0) { bp[i] = 0u; bp[NIN + i] = 0u; }   // guard rows
    } else if (blk < 576) {
        int idx = (blk - 512) * 256 + tid;    // 16384 = g*1024 + h
        int g = idx >> 10, h = idx & 1023;
        const float* Wp = W    + (size_t)h * NIN + 8 * g;
        const float* Rp = draw + (size_t)h * NIN + 8 * g;
        uint32_t s0 = 0, s1 = 0, wq = 0;
        const int ordm[8] = {0, 4, 1, 5, 2, 6, 3, 7};
        #pragma unroll
        for (int j = 0; j < 4; ++j) {
            int sp_a = 63 - (int)rintf(50.0f / (1.0f + expf(-Rp[j])));      // RNE = jnp.round
            int sp_b = 63 - (int)rintf(50.0f / (1.0f + expf(-Rp[4 + j])));
            s0 |= (uint32_t)sp_a << (8 * j);
            s1 |= (uint32_t)sp_b << (8 * j);
        }
        #pragma unroll
        for (int m = 0; m < 8; ++m) {
            int q = (int)rintf(fminf(fmaxf(Wp[ordm[m]] * WSCALE, -8.0f), 7.0f));
            wq |= ((uint32_t)q & 0xFu) << (4 * m);
        }
        pk4[(size_t)g * NHID + h] = make_uint4(s0, s1, wq, 0u);
    } else {
        int idx = (blk - 576) * 256 + tid;    // 1280 outputs
        if (idx < B_DIM * KSLOT) out[idx] = b_ro[0];
        else if (idx < B_DIM * KSLOT + T_DIM) out[idx] = 0.0f;
    }
}

// ---------------- fused sdot8 mask-ladder + wave-relay LIF ----------------
// block = (b, hg of 64 h), 512 threads = 8 waves, grid 512.
// R13 = R11 (session-best, 88 us) + single ds_read_b128 for per-g params.
// R12 lesson: NO software pipelining — double-buffered staging spilled acc[] to
// scratch (WRITE_SIZE 128 KB -> 1.9 GB, 20x regression). With acc[32] resident,
// register headroom under launch_bounds(512,4) admits no extra prefetch set.
__global__ __launch_bounds__(512, 4) void fused_kernel(
    const uint4* __restrict__ pk4, const uint32_t* __restrict__ xbitsT,
    float* __restrict__ out, const float* __restrict__ w_ro,
    const int* __restrict__ ss, const int* __restrict__ se) {
    __shared__ uint32_t lds_x[NWORDS * NIN];  // [w][i]   17 KB (transposed)
    __shared__ uint4    lds_pk[NG * 64];      // [g][hl]  16 KB {sp lo, sp hi, wq, pad}
    __shared__ float st_v[64];
    __shared__ float st_rf[64];
    __shared__ float st_sacc[KSLOT][64];      // authoritative (lazy relay)
    __shared__ int   flag;

    int bx = blockIdx.x;
    int hg = bx & 15;
    int b  = bx >> 4;
    int tid  = threadIdx.x;
    int lane = tid & 63;
    int sub  = tid >> 6;
    int hbase = hg * 64;

    for (int idx = tid; idx < NWORDS * NIN; idx += 512)
        lds_x[idx] = xbitsT[(size_t)b * NWORDS * NIN + idx];
    for (int idx = tid; idx < NG * 64; idx += 512) {
        int g = idx >> 6, hl = idx & 63;
        lds_pk[idx] = pk4[(size_t)g * NHID + hbase + hl];
    }
    if (tid < 64) { st_v[tid] = 0.0f; st_rf[tid] = 0.0f; }
    if (tid < KSLOT * 64) ((float*)st_sacc)[tid] = 0.0f;
    if (tid == 0) flag = 0;
    __syncthreads();

    int st_[KSLOT], en_[KSLOT];
    #pragma unroll
    for (int k = 0; k < KSLOT; ++k) {
        st_[k] = __builtin_amdgcn_readfirstlane(ss[k]);
        en_[k] = __builtin_amdgcn_readfirstlane(se[k]);
    }

    for (int rl = 0; rl < ROUNDS; ++rl) {
        int c  = __builtin_amdgcn_readfirstlane(rl * WAVES + sub);
        int t0 = c * 32;
        int acc[32];
        #pragma unroll
        for (int k = 0; k < 32; ++k) acc[k] = 0;
        const uint32_t* xrow = lds_x + c * NIN;   // per-chunk base; offsets immediate
        #pragma unroll 2
        for (int g = 0; g < NG; ++g) {
            uint4 pkc = lds_pk[(g << 6) | lane];  // one ds_read_b128: {sp lo, sp hi, wq}
            uint32_t wq = pkc.z;
            uint32_t win[8];
            {   // half 0: streams 8g..8g+3 — 3 uniform b128; consume fields directly
                uint4 a  = *(const uint4*)(xrow + 8 * g);
                uint4 bq = *(const uint4*)(xrow + NIN + 8 * g);
                uint4 cq = *(const uint4*)(xrow + 2 * NIN + 8 * g);
                win[0] = mkwin(pkc.x & 0xFFu,         a.x, bq.x, cq.x);
                win[1] = mkwin((pkc.x >> 8) & 0xFFu,  a.y, bq.y, cq.y);
                win[2] = mkwin((pkc.x >> 16) & 0xFFu, a.z, bq.z, cq.z);
                win[3] = mkwin(pkc.x >> 24,           a.w, bq.w, cq.w);
            }
            {   // half 1: streams 8g+4..8g+7
                uint4 a  = *(const uint4*)(xrow + 8 * g + 4);
                uint4 bq = *(const uint4*)(xrow + NIN + 8 * g + 4);
                uint4 cq = *(const uint4*)(xrow + 2 * NIN + 8 * g + 4);
                win[4] = mkwin(pkc.y & 0xFFu,         a.x, bq.x, cq.x);
                win[5] = mkwin((pkc.y >> 8) & 0xFFu,  a.y, bq.y, cq.y);
                win[6] = mkwin((pkc.y >> 16) & 0xFFu, a.z, bq.z, cq.z);
                win[7] = mkwin(pkc.y >> 24,           a.w, bq.w, cq.w);
            }
            // ---- byte-interleave; X nibble order [s0,s4,s1,s5,s2,s6,s3,s7] = wq packing ----
            uint32_t A0 = permb(win[1], win[0], 0x05010400u);
            uint32_t B0 = permb(win[1], win[0], 0x07030602u);
            uint32_t C0 = permb(win[3], win[2], 0x05010400u);
            uint32_t D0 = permb(win[3], win[2], 0x07030602u);
            uint32_t A1 = permb(win[5], win[4], 0x05010400u);
            uint32_t B1 = permb(win[5], win[4], 0x07030602u);
            uint32_t C1 = permb(win[7], win[6], 0x05010400u);
            uint32_t D1 = permb(win[7], win[6], 0x07030602u);
            {
                uint32_t P = permb(C0, A0, 0x05040100u);
                uint32_t Q = permb(C1, A1, 0x05040100u);
                uint32_t X0 = (P & 0x0F0F0F0Fu) | ((Q << 4) & 0xF0F0F0F0u);
                uint32_t X1 = ((P >> 4) & 0x0F0F0F0Fu) | (Q & 0xF0F0F0F0u);
                acc[0] = dot8acc(X0 & 0x11111111u, wq, acc[0]);   // 1x
                acc[1] = dot8acc(X0 & 0x22222222u, wq, acc[1]);   // 2x
                acc[2] = dot8acc(X0 & 0x44444444u, wq, acc[2]);   // 4x
                acc[3] = dot8acc(X0 & 0x88888888u, wq, acc[3]);   // -8x
                acc[4] = dot8acc(X1 & 0x11111111u, wq, acc[4]);
                acc[5] = dot8acc(X1 & 0x22222222u, wq, acc[5]);
                acc[6] = dot8acc(X1 & 0x44444444u, wq, acc[6]);
                acc[7] = dot8acc(X1 & 0x88888888u, wq, acc[7]);
            }
            {
                uint32_t P = permb(C0, A0, 0x07060302u);
                uint32_t Q = permb(C1, A1, 0x07060302u);
                uint32_t X2 = (P & 0x0F0F0F0Fu) | ((Q << 4) & 0xF0F0F0F0u);
                uint32_t X3 = ((P >> 4) & 0x0F0F0F0Fu) | (Q & 0xF0F0F0F0u);
                acc[8]  = dot8acc(X2 & 0x11111111u, wq, acc[8]);
                acc[9]  = dot8acc(X2 & 0x22222222u, wq, acc[9]);
                acc[10] = dot8acc(X2 & 0x44444444u, wq, acc[10]);
                acc[11] = dot8acc(X2 & 0x88888888u, wq, acc[11]);
                acc[12] = dot8acc(X3 & 0x11111111u, wq, acc[12]);
                acc[13] = dot8acc(X3 & 0x22222222u, wq, acc[13]);
                acc[14] = dot8acc(X3 & 0x44444444u, wq, acc[14]);
                acc[15] = dot8acc(X3 & 0x88888888u, wq, acc[15]);
            }
            {
                uint32_t P = permb(D0, B0, 0x05040100u);
                uint32_t Q = permb(D1, B1, 0x05040100u);
                uint32_t X4 = (P & 0x0F0F0F0Fu) | ((Q << 4) & 0xF0F0F0F0u);
                uint32_t X5 = ((P >> 4) & 0x0F0F0F0Fu) | (Q & 0xF0F0F0F0u);
                acc[16] = dot8acc(X4 & 0x11111111u, wq, acc[16]);
                acc[17] = dot8acc(X4 & 0x22222222u, wq, acc[17]);
                acc[18] = dot8acc(X4 & 0x44444444u, wq, acc[18]);
                acc[19] = dot8acc(X4 & 0x88888888u, wq, acc[19]);
                acc[20] = dot8acc(X5 & 0x11111111u, wq, acc[20]);
                acc[21] = dot8acc(X5 & 0x22222222u, wq, acc[21]);
                acc[22] = dot8acc(X5 & 0x44444444u, wq, acc[22]);
                acc[23] = dot8acc(X5 & 0x88888888u, wq, acc[23]);
            }
            {
                uint32_t P = permb(D0, B0, 0x07060302u);
                uint32_t Q = permb(D1, B1, 0x07060302u);
                uint32_t X6 = (P & 0x0F0F0F0Fu) | ((Q << 4) & 0xF0F0F0F0u);
                uint32_t X7 = ((P >> 4) & 0x0F0F0F0Fu) | (Q & 0xF0F0F0F0u);
                acc[24] = dot8acc(X6 & 0x11111111u, wq, acc[24]);
                acc[25] = dot8acc(X6 & 0x22222222u, wq, acc[25]);
                acc[26] = dot8acc(X6 & 0x44444444u, wq, acc[26]);
                acc[27] = dot8acc(X6 & 0x88888888u, wq, acc[27]);
                acc[28] = dot8acc(X7 & 0x11111111u, wq, acc[28]);
                acc[29] = dot8acc(X7 & 0x22222222u, wq, acc[29]);
                acc[30] = dot8acc(X7 & 0x44444444u, wq, acc[30]);
                acc[31] = dot8acc(X7 & 0x88888888u, wq, acc[31]);
            }
        }
        // ---- relay: wait for token ----
        while (__builtin_amdgcn_readfirstlane(*(volatile int*)&flag) != c)
            __builtin_amdgcn_s_sleep(1);
        float v  = st_v[lane];
        float rf = st_rf[lane];
        // ---- LIF fast path (exact detection of slow-path need) ----
        float vf = v, vmax = -1.0f;
        #pragma unroll
        for (int k = 0; k < 32; ++k) {
            float sc = ((k & 3) == 0) ? SC0 : ((k & 3) == 1) ? SC1 : ((k & 3) == 2) ? SC2 : SC3;
            float I = (float)acc[k] * sc;
            vf = vf + 0.1f * (I - vf);
            vmax = fmaxf(vmax, vf);
        }
        bool slow = (rf > 0.0f) || (vmax >= 1.0f);
        if (__ballot(slow) != 0ULL) {
            // ---- exact path (rare: >=7 sigma margin) ----
            float sacc[KSLOT];
            #pragma unroll
            for (int k = 0; k < KSLOT; ++k) sacc[k] = st_sacc[k][lane];
            #pragma unroll
            for (int k = 0; k < 32; ++k) {
                float sc = ((k & 3) == 0) ? SC0 : ((k & 3) == 1) ? SC1 : ((k & 3) == 2) ? SC2 : SC3;
                float I = (float)acc[k] * sc;
                int t = t0 + k;
                bool active = (rf <= 0.0f);
                float vupd = v + 0.1f * (I - v);
                float vn = active ? vupd : v;
                bool spike = active && (vn >= 1.0f);
                unsigned long long bal = __ballot(spike);
                if (bal != 0ULL) {
                    if (spike) {
                        vn = 0.0f;                // V_RESET
                        #pragma unroll
                        for (int k2 = 0; k2 < KSLOT; ++k2)
                            if (t >= st_[k2] && t < en_[k2]) sacc[k2] += 1.0f;
                    }
                    rf = spike ? 2.0f : fmaxf(rf - 1.0f, 0.0f);
                    if (lane == 0) atomicAdd(&out[B_DIM * KSLOT + t], (float)__popcll(bal));
                } else {
                    rf = fmaxf(rf - 1.0f, 0.0f);
                }
                v = vn;
            }
            #pragma unroll
            for (int k = 0; k < KSLOT; ++k) st_sacc[k][lane] = sacc[k];
        } else {
            v = vf;
            rf = 0.0f;
        }
        st_v[lane]  = v;
        st_rf[lane] = rf;
        __threadfence_block();                     // drain LDS writes before flag release
        if (lane == 0) *(volatile int*)&flag = c + 1;
    }
    // ---- epilogue: after chunk 31's relay write, LDS sacc is final ----
    if (sub == WAVES - 1) {
        float wr = w_ro[hbase + lane];
        #pragma unroll
        for (int k = 0; k < KSLOT; ++k) {
            float val = st_sacc[k][lane] * wr;
            #pragma unroll
            for (int o = 32; o > 0; o >>= 1) val += __shfl_down(val, o);
            if (lane == 0) atomicAdd(&out[b * KSLOT + k], val);
        }
    }
}

extern "C" void kernel_launch(void* const* d_in, const int* in_sizes, int n_in,
                              void* d_out, int out_size, void* d_ws, size_t ws_size,
                              hipStream_t stream) {
    const float* x   = (const float*)d_in[0];
    const float* W   = (const float*)d_in[1];
    const float* drw = (const float*)d_in[2];
    const float* wro = (const float*)d_in[3];
    const float* bro = (const float*)d_in[4];
    const int*   ss  = (const int*)d_in[5];
    const int*   se  = (const int*)d_in[6];
    float* out = (float*)d_out;

    uintptr_t base = (uintptr_t)d_ws;
    size_t off = 0;
    auto take = [&](size_t bytes) {
        size_t o = off;
        off = (off + bytes + 255) & ~(size_t)255;
        return (void*)(base + o);
    };
    uint32_t* xbitsT = (uint32_t*)take((size_t)B_DIM * NWORDS * NIN * 4);
    uint4*    pk4    = (uint4*)take((size_t)NG * NHID * 16);
    (void)ws_size;

    prep_kernel<<<581, 256, 0, stream>>>(x, W, drw, bro, xbitsT, pk4, out);
    fused_kernel<<<512, 512, 0, stream>>>(pk4, xbitsT, out, wro, ss, se);
}